// Round 8
// baseline (122.488 us; speedup 1.0000x reference)
//
#include <hip/hip_runtime.h>
#include <math.h>

#define Bsz 16
#define Gg  20000
#define Dd  256
#define Kk  2048
#define NB  8192          // 13-bit key bins: key = bits>>17
#define CCAP 2048
#define TBL_N 1024

__device__ __forceinline__ float gelu_exact(float x) {
  return 0.5f * x * (1.0f + erff(x * 0.70710678118654752f));
}

// exclusive scan over 1024 threads (16 waves); leading barrier protects s_ws reuse
__device__ __forceinline__ unsigned scan1024_excl(unsigned v, unsigned* s_ws,
                                                  unsigned* tot) {
  const int lane = threadIdx.x & 63, wid = threadIdx.x >> 6;
  __syncthreads();
  unsigned incl = v;
  #pragma unroll
  for (int off = 1; off < 64; off <<= 1) {
    unsigned u = (unsigned)__shfl_up((int)incl, off);
    if (lane >= off) incl += u;
  }
  if (lane == 63) s_ws[wid] = incl;
  __syncthreads();
  if (wid == 0) {
    unsigned w = (lane < 16) ? s_ws[lane] : 0u;
    unsigned wi = w;
    #pragma unroll
    for (int off = 1; off < 16; off <<= 1) {
      unsigned u = (unsigned)__shfl_up((int)wi, off);
      if (lane >= off) wi += u;
    }
    if (lane < 16) s_ws[lane] = wi - w;
    if (lane == 15) s_ws[16] = wi;
  }
  __syncthreads();
  if (tot) *tot = s_ws[16];
  return s_ws[wid] + incl - v;
}

// ===== kernel 1: per-row full selection (blocks 0..15) ∥ F-table 16 nodes/block (16..80) =====
__global__ __launch_bounds__(1024) void k_main(
    const float* __restrict__ expr,
    const float* __restrict__ w1, const float* __restrict__ b1,
    const float* __restrict__ w2, const float* __restrict__ b2,
    const float* __restrict__ cls,
    int* __restrict__ comp_idx, float* __restrict__ expr_sel,
    float* __restrict__ F, float* __restrict__ out)
{
  union SM {
    struct { unsigned hist[NB]; unsigned cand[CCAP]; } sel;    // 40 KB
    struct { float h16[16][256]; float t[32][257]; } tab;      // 48.9 KB
  };
  __shared__ SM u;
  __shared__ unsigned s_ws[17];
  __shared__ unsigned s_B, s_needbin, s_remK, s_cnt, s_T, s_ne, s_rankT;
  __shared__ int s_done;
  const int tid = threadIdx.x;

  if (blockIdx.x >= Bsz) {
    // ---- table role: 16 nodes per block; F[j][e] = (W2.gelu(x_j*w1+b1)+b2)[e] ----
    const int j0 = (blockIdx.x - Bsz) * 16;
    const int e  = tid & 255;
    const int jj = tid >> 8;                 // 0..3, wave-uniform
    {
      const float w = w1[e], bb = b1[e];
      #pragma unroll
      for (int k = 0; k < 4; ++k) {
        int node = jj * 4 + k;
        float xj = (float)(j0 + node) * (1.0f / TBL_N);
        u.tab.h16[node][e] = gelu_exact(xj * w + bb);
      }
    }
    float acc[4] = {0.f, 0.f, 0.f, 0.f};
    const int er = tid >> 3, q = tid & 7;    // stage: 128 rows x 8 d-quads
    #pragma unroll 1
    for (int c = 0; c < 8; ++c) {
      __syncthreads();                        // h16 ready (c==0) / prev compute done
      #pragma unroll
      for (int half = 0; half < 2; ++half) {
        int r = er + half * 128;
        float4 wv = *(const float4*)(w2 + (size_t)r * 256 + c * 32 + q * 4);
        u.tab.t[q * 4 + 0][r] = wv.x;
        u.tab.t[q * 4 + 1][r] = wv.y;
        u.tab.t[q * 4 + 2][r] = wv.z;
        u.tab.t[q * 4 + 3][r] = wv.w;
      }
      __syncthreads();
      #pragma unroll
      for (int dd = 0; dd < 32; ++dd) {
        float tv = u.tab.t[dd][e];
        #pragma unroll
        for (int k = 0; k < 4; ++k)
          acc[k] += u.tab.h16[jj * 4 + k][c * 32 + dd] * tv;
      }
    }
    const float bv = b2[e];
    #pragma unroll
    for (int k = 0; k < 4; ++k) {
      int j = j0 + jj * 4 + k;
      if (j <= TBL_N) F[(size_t)j * Dd + e] = bv + acc[k];
    }
    return;
  }

  // ---- selection role: one block per batch row ----
  const int b = blockIdx.x;
  const float4* row4 = (const float4*)(expr + (size_t)b * Gg);

  if (tid == 0) { s_remK = Kk; s_done = 0; s_cnt = 0; }
  for (int i = tid; i < NB; i += 1024) u.sel.hist[i] = 0u;
  __syncthreads();

  // phase 1: LDS histogram
  #pragma unroll
  for (int it = 0; it < 5; ++it) {
    int idx = it * 1024 + tid;
    if (idx < Gg / 4) {
      float4 v = row4[idx];
      #pragma unroll
      for (int j = 0; j < 4; ++j) {
        unsigned k = __float_as_uint(((const float*)&v)[j]) >> 17;
        if (k > NB - 1) k = NB - 1;
        atomicAdd(&u.sel.hist[k], 1u);
      }
    }
  }
  __syncthreads();

  // phase 2: find 13-bit bin of the K-th largest (descending chunks of 1024 bins)
  for (int c = 0; c < NB / 1024 && !s_done; ++c) {
    const int idx = NB - 1 - c * 1024 - tid;
    unsigned partial = u.sel.hist[idx];
    unsigned tot;
    unsigned excl = scan1024_excl(partial, s_ws, &tot);
    const unsigned remK = s_remK;
    if (excl < remK && remK <= excl + partial) {
      s_B = (unsigned)idx; s_needbin = remK - excl; s_done = 1;
    }
    __syncthreads();
    if (!s_done && tid == 0) s_remK = remK - tot;
    __syncthreads();
  }
  const unsigned B = s_B, needbin = s_needbin;

  // phase 3: collect candidates with key == B (row L2-hot)
  #pragma unroll
  for (int it = 0; it < 5; ++it) {
    int idx = it * 1024 + tid;
    if (idx < Gg / 4) {
      float4 v = row4[idx];
      #pragma unroll
      for (int j = 0; j < 4; ++j) {
        unsigned bits = __float_as_uint(((const float*)&v)[j]);
        if ((bits >> 17) == B) {
          unsigned p = atomicAdd(&s_cnt, 1u);
          if (p < CCAP) u.sel.cand[p] = bits;
        }
      }
    }
  }
  __syncthreads();
  const unsigned n = (s_cnt < CCAP) ? s_cnt : CCAP;

  // phase 4: exact 32-bit threshold among candidates (tie-aware)
  for (unsigned i = tid; i < n; i += 1024) {
    unsigned v = u.sel.cand[i];
    unsigned rank = 0, eq = 0;
    for (unsigned j = 0; j < n; ++j) {
      unsigned uu = u.sel.cand[j];
      rank += (uu > v) ? 1u : 0u;
      eq   += (uu == v) ? 1u : 0u;
    }
    if (rank < needbin && needbin <= rank + eq) {
      s_T = v; s_ne = needbin - rank; s_rankT = rank;  // unique value class
    }
  }
  __syncthreads();
  const unsigned T = s_T;
  const unsigned need_eq = (T == 0u) ? 0u : s_ne;
  const unsigned n_b = (Kk - needbin) + s_rankT + need_eq;

  // phase 5: compaction (3 chunks x 8192 elems, 8 per thread, running bases)
  unsigned base_gt = 0, base_eq = 0;
  #pragma unroll 1
  for (int c = 0; c < 3; ++c) {
    const int g0 = c * 8192 + tid * 8;
    const bool act = g0 < Gg;
    float4 va = {0.f, 0.f, 0.f, 0.f}, vb = {0.f, 0.f, 0.f, 0.f};
    unsigned gt = 0, eq = 0;
    if (act) {
      va = row4[(g0 >> 2) + 0];
      vb = row4[(g0 >> 2) + 1];
      #pragma unroll
      for (int j = 0; j < 4; ++j) {
        unsigned ba = __float_as_uint(((const float*)&va)[j]);
        unsigned bb2 = __float_as_uint(((const float*)&vb)[j]);
        gt += (ba > T) ? 1u : 0u;  eq += (ba == T) ? 1u : 0u;
        gt += (bb2 > T) ? 1u : 0u; eq += (bb2 == T) ? 1u : 0u;
      }
    }
    unsigned tot;
    unsigned excl = scan1024_excl((gt << 16) | eq, s_ws, &tot);
    unsigned thr_gt = base_gt + (excl >> 16);
    unsigned thr_eq = base_eq + (excl & 0xFFFFu);
    if (act) {
      unsigned lgt = 0, leq = 0;
      #pragma unroll
      for (int jj = 0; jj < 8; ++jj) {
        float vj = (jj < 4) ? ((const float*)&va)[jj] : ((const float*)&vb)[jj - 4];
        unsigned bits = __float_as_uint(vj);
        unsigned cur_gt = thr_gt + lgt, cur_eq = thr_eq + leq;
        bool isgt = bits > T, iseq = bits == T;
        bool kept = isgt || (iseq && cur_eq < need_eq);
        if (kept) {
          unsigned pos = cur_gt + ((cur_eq < need_eq) ? cur_eq : need_eq);
          comp_idx[b * Kk + pos] = g0 + jj;
          expr_sel[b * Kk + pos] = vj;
        }
        lgt += isgt ? 1u : 0u;
        leq += iseq ? 1u : 0u;
      }
    }
    base_gt += tot >> 16;
    base_eq += tot & 0xFFFFu;
  }

  // phase 6: padding, cls token, mask
  for (int k = (int)n_b + tid; k < Kk; k += 1024) {
    comp_idx[b * Kk + k] = -1;
    expr_sel[b * Kk + k] = 0.0f;
  }
  if (tid < Dd) out[(size_t)b * (Kk + 1) * Dd + tid] = cls[tid];
  float* maskp = out + (size_t)Bsz * (Kk + 1) * Dd + (size_t)b * (Kk + 1);
  for (int i = tid; i <= Kk; i += 1024)
    maskp[i] = (i == 0) ? 1.0f : (((unsigned)(i - 1) < n_b) ? 1.0f : 0.0f);
}

// ============ kernel 2: gather tokens via table lerp (fully coalesced) ============
__global__ __launch_bounds__(256) void k_gather(
    const int* __restrict__ comp_idx, const float* __restrict__ expr_sel,
    const float* __restrict__ F, const float* __restrict__ gene_emb,
    float* __restrict__ out)
{
  const int tid  = threadIdx.x;
  const int slot = blockIdx.x * 4 + (tid >> 6);
  const int lane = tid & 63;
  const int e0   = lane * 4;

  const int g  = comp_idx[slot];
  const int bb = slot >> 11, k = slot & 2047;
  float* op = out + (size_t)bb * ((Kk + 1) * Dd) + (size_t)(k + 1) * Dd + e0;

  float4 o = {0.f, 0.f, 0.f, 0.f};
  if (g >= 0) {
    float x  = expr_sel[slot];
    float xs = x * (float)TBL_N;
    int j = (int)xs;
    j = (j < 0) ? 0 : ((j > TBL_N - 1) ? TBL_N - 1 : j);
    float t = xs - (float)j;
    const float* fa = F + (size_t)j * Dd + e0;
    float4 a  = *(const float4*)fa;
    float4 bv = *(const float4*)(fa + Dd);
    float4 ge = *(const float4*)(gene_emb + (size_t)g * Dd + e0);
    o.x = ge.x + a.x + (bv.x - a.x) * t;
    o.y = ge.y + a.y + (bv.y - a.y) * t;
    o.z = ge.z + a.z + (bv.z - a.z) * t;
    o.w = ge.w + a.w + (bv.w - a.w) * t;
  }
  *(float4*)op = o;
}

extern "C" void kernel_launch(void* const* d_in, const int* in_sizes, int n_in,
                              void* d_out, int out_size, void* d_ws, size_t ws_size,
                              hipStream_t stream)
{
  const float* expr     = (const float*)d_in[0];
  const float* gene_emb = (const float*)d_in[1];
  const float* w1       = (const float*)d_in[2];
  const float* b1       = (const float*)d_in[3];
  const float* w2       = (const float*)d_in[4];
  const float* b2       = (const float*)d_in[5];
  const float* cls      = (const float*)d_in[6];
  float* out = (float*)d_out;

  float* F        = (float*)d_ws;                               // 1.05 MB
  int*   comp_idx = (int*)((char*)d_ws + (1280 << 10));         // 128 KB
  float* expr_sel = (float*)((char*)d_ws + (1408 << 10));       // 128 KB

  hipLaunchKernelGGL(k_main,   dim3(Bsz + 65),       dim3(1024), 0, stream,
                     expr, w1, b1, w2, b2, cls, comp_idx, expr_sel, F, out);
  hipLaunchKernelGGL(k_gather, dim3((Bsz * Kk) / 4), dim3(256),  0, stream,
                     comp_idx, expr_sel, F, gene_emb, out);
}

// Round 9
// 116.685 us; speedup vs baseline: 1.0497x; 1.0497x over previous
//
#include <hip/hip_runtime.h>
#include <math.h>

#define Bsz 16
#define Gg  20000
#define Dd  256
#define Kk  2048
#define NB  8192          // 13-bit key bins: key = bits>>17
#define CCAP 2048
#define TBL_N 1024

__device__ __forceinline__ float gelu_exact(float x) {
  return 0.5f * x * (1.0f + erff(x * 0.70710678118654752f));
}

// exclusive scan over 1024 threads (16 waves); leading barrier protects s_ws reuse
__device__ __forceinline__ unsigned scan1024_excl(unsigned v, unsigned* s_ws,
                                                  unsigned* tot) {
  const int lane = threadIdx.x & 63, wid = threadIdx.x >> 6;
  __syncthreads();
  unsigned incl = v;
  #pragma unroll
  for (int off = 1; off < 64; off <<= 1) {
    unsigned u = (unsigned)__shfl_up((int)incl, off);
    if (lane >= off) incl += u;
  }
  if (lane == 63) s_ws[wid] = incl;
  __syncthreads();
  if (wid == 0) {
    unsigned w = (lane < 16) ? s_ws[lane] : 0u;
    unsigned wi = w;
    #pragma unroll
    for (int off = 1; off < 16; off <<= 1) {
      unsigned u = (unsigned)__shfl_up((int)wi, off);
      if (lane >= off) wi += u;
    }
    if (lane < 16) s_ws[lane] = wi - w;
    if (lane == 15) s_ws[16] = wi;
  }
  __syncthreads();
  if (tot) *tot = s_ws[16];
  return s_ws[wid] + incl - v;
}

// ===== kernel 1: per-row full selection (blocks 0..15) ∥ F-table 4 nodes/block (16..272) =====
__global__ __launch_bounds__(1024) void k_main(
    const float* __restrict__ expr,
    const float* __restrict__ w1, const float* __restrict__ b1,
    const float* __restrict__ w2, const float* __restrict__ b2,
    const float* __restrict__ cls,
    int* __restrict__ comp_idx, float* __restrict__ expr_sel,
    float* __restrict__ F, float* __restrict__ out)
{
  union SM {
    struct { unsigned hist[NB]; unsigned cand[CCAP]; } sel;     // 40 KB
    struct { float h4[4][256]; float tr[256][33]; } tab;        // 37.8 KB
  };
  __shared__ SM u;
  __shared__ unsigned s_ws[17];
  __shared__ unsigned s_B, s_needbin, s_remK, s_cnt, s_T, s_ne, s_rankT;
  __shared__ int s_done;
  const int tid = threadIdx.x;

  if (blockIdx.x >= Bsz) {
    // ---- table role: 4 nodes per block; F[j][e] = (W2.gelu(x_j*w1+b1)+b2)[e] ----
    const int j0 = (blockIdx.x - Bsz) * 4;
    const int e  = tid & 255;
    const int jj = tid >> 8;                 // 0..3, wave-uniform
    {
      float xj = (float)(j0 + jj) * (1.0f / TBL_N);
      u.tab.h4[jj][e] = gelu_exact(xj * w1[e] + b1[e]);
    }
    float acc = 0.f;
    const int er = tid >> 3, q = tid & 7;    // stage: 128 rows x 8 d-quads per half
    #pragma unroll 1
    for (int c = 0; c < 8; ++c) {
      __syncthreads();                        // h4 ready (c==0) / prev compute done
      #pragma unroll
      for (int half = 0; half < 2; ++half) {
        int r = er + half * 128;
        *(float4*)&u.tab.tr[r][q * 4] =
            *(const float4*)(w2 + (size_t)r * 256 + c * 32 + q * 4);
      }
      __syncthreads();
      #pragma unroll
      for (int dq = 0; dq < 8; ++dq) {
        float4 hv = *(const float4*)&u.tab.h4[jj][c * 32 + dq * 4];  // broadcast b128
        float4 tv = *(const float4*)&u.tab.tr[e][dq * 4];            // 2-way, free
        acc += hv.x * tv.x + hv.y * tv.y + hv.z * tv.z + hv.w * tv.w;
      }
    }
    const int j = j0 + jj;
    if (j <= TBL_N) F[(size_t)j * Dd + e] = b2[e] + acc;
    return;
  }

  // ---- selection role: one block per batch row ----
  const int b = blockIdx.x;
  const float4* row4 = (const float4*)(expr + (size_t)b * Gg);

  if (tid == 0) { s_remK = Kk; s_done = 0; s_cnt = 0; }
  for (int i = tid; i < NB; i += 1024) u.sel.hist[i] = 0u;
  __syncthreads();

  // phase 1: LDS histogram
  #pragma unroll
  for (int it = 0; it < 5; ++it) {
    int idx = it * 1024 + tid;
    if (idx < Gg / 4) {
      float4 v = row4[idx];
      #pragma unroll
      for (int j = 0; j < 4; ++j) {
        unsigned k = __float_as_uint(((const float*)&v)[j]) >> 17;
        if (k > NB - 1) k = NB - 1;
        atomicAdd(&u.sel.hist[k], 1u);
      }
    }
  }
  __syncthreads();

  // phase 2: find 13-bit bin of the K-th largest (descending chunks of 1024 bins)
  for (int c = 0; c < NB / 1024 && !s_done; ++c) {
    const int idx = NB - 1 - c * 1024 - tid;
    unsigned partial = u.sel.hist[idx];
    unsigned tot;
    unsigned excl = scan1024_excl(partial, s_ws, &tot);
    const unsigned remK = s_remK;
    if (excl < remK && remK <= excl + partial) {
      s_B = (unsigned)idx; s_needbin = remK - excl; s_done = 1;
    }
    __syncthreads();
    if (!s_done && tid == 0) s_remK = remK - tot;
    __syncthreads();
  }
  const unsigned B = s_B, needbin = s_needbin;

  // phase 3: collect candidates with key == B (row L2-hot)
  #pragma unroll
  for (int it = 0; it < 5; ++it) {
    int idx = it * 1024 + tid;
    if (idx < Gg / 4) {
      float4 v = row4[idx];
      #pragma unroll
      for (int j = 0; j < 4; ++j) {
        unsigned bits = __float_as_uint(((const float*)&v)[j]);
        if ((bits >> 17) == B) {
          unsigned p = atomicAdd(&s_cnt, 1u);
          if (p < CCAP) u.sel.cand[p] = bits;
        }
      }
    }
  }
  __syncthreads();
  const unsigned n = (s_cnt < CCAP) ? s_cnt : CCAP;

  // phase 4: exact 32-bit threshold among candidates (tie-aware)
  for (unsigned i = tid; i < n; i += 1024) {
    unsigned v = u.sel.cand[i];
    unsigned rank = 0, eq = 0;
    for (unsigned j = 0; j < n; ++j) {
      unsigned uu = u.sel.cand[j];
      rank += (uu > v) ? 1u : 0u;
      eq   += (uu == v) ? 1u : 0u;
    }
    if (rank < needbin && needbin <= rank + eq) {
      s_T = v; s_ne = needbin - rank; s_rankT = rank;  // unique value class
    }
  }
  __syncthreads();
  const unsigned T = s_T;
  const unsigned need_eq = (T == 0u) ? 0u : s_ne;
  const unsigned n_b = (Kk - needbin) + s_rankT + need_eq;

  // phase 5: compaction (3 chunks x 8192 elems, 8 per thread, running bases)
  unsigned base_gt = 0, base_eq = 0;
  #pragma unroll 1
  for (int c = 0; c < 3; ++c) {
    const int g0 = c * 8192 + tid * 8;
    const bool act = g0 < Gg;
    float4 va = {0.f, 0.f, 0.f, 0.f}, vb = {0.f, 0.f, 0.f, 0.f};
    unsigned gt = 0, eq = 0;
    if (act) {
      va = row4[(g0 >> 2) + 0];
      vb = row4[(g0 >> 2) + 1];
      #pragma unroll
      for (int j = 0; j < 4; ++j) {
        unsigned ba = __float_as_uint(((const float*)&va)[j]);
        unsigned bb2 = __float_as_uint(((const float*)&vb)[j]);
        gt += (ba > T) ? 1u : 0u;  eq += (ba == T) ? 1u : 0u;
        gt += (bb2 > T) ? 1u : 0u; eq += (bb2 == T) ? 1u : 0u;
      }
    }
    unsigned tot;
    unsigned excl = scan1024_excl((gt << 16) | eq, s_ws, &tot);
    unsigned thr_gt = base_gt + (excl >> 16);
    unsigned thr_eq = base_eq + (excl & 0xFFFFu);
    if (act) {
      unsigned lgt = 0, leq = 0;
      #pragma unroll
      for (int jj = 0; jj < 8; ++jj) {
        float vj = (jj < 4) ? ((const float*)&va)[jj] : ((const float*)&vb)[jj - 4];
        unsigned bits = __float_as_uint(vj);
        unsigned cur_gt = thr_gt + lgt, cur_eq = thr_eq + leq;
        bool isgt = bits > T, iseq = bits == T;
        bool kept = isgt || (iseq && cur_eq < need_eq);
        if (kept) {
          unsigned pos = cur_gt + ((cur_eq < need_eq) ? cur_eq : need_eq);
          comp_idx[b * Kk + pos] = g0 + jj;
          expr_sel[b * Kk + pos] = vj;
        }
        lgt += isgt ? 1u : 0u;
        leq += iseq ? 1u : 0u;
      }
    }
    base_gt += tot >> 16;
    base_eq += tot & 0xFFFFu;
  }

  // phase 6: padding, cls token, mask
  for (int k = (int)n_b + tid; k < Kk; k += 1024) {
    comp_idx[b * Kk + k] = -1;
    expr_sel[b * Kk + k] = 0.0f;
  }
  if (tid < Dd) out[(size_t)b * (Kk + 1) * Dd + tid] = cls[tid];
  float* maskp = out + (size_t)Bsz * (Kk + 1) * Dd + (size_t)b * (Kk + 1);
  for (int i = tid; i <= Kk; i += 1024)
    maskp[i] = (i == 0) ? 1.0f : (((unsigned)(i - 1) < n_b) ? 1.0f : 0.0f);
}

// ============ kernel 2: gather tokens via table lerp (fully coalesced) ============
__global__ __launch_bounds__(256) void k_gather(
    const int* __restrict__ comp_idx, const float* __restrict__ expr_sel,
    const float* __restrict__ F, const float* __restrict__ gene_emb,
    float* __restrict__ out)
{
  const int tid  = threadIdx.x;
  const int slot = blockIdx.x * 4 + (tid >> 6);
  const int lane = tid & 63;
  const int e0   = lane * 4;

  const int g  = comp_idx[slot];
  const int bb = slot >> 11, k = slot & 2047;
  float* op = out + (size_t)bb * ((Kk + 1) * Dd) + (size_t)(k + 1) * Dd + e0;

  float4 o = {0.f, 0.f, 0.f, 0.f};
  if (g >= 0) {
    float x  = expr_sel[slot];
    float xs = x * (float)TBL_N;
    int j = (int)xs;
    j = (j < 0) ? 0 : ((j > TBL_N - 1) ? TBL_N - 1 : j);
    float t = xs - (float)j;
    const float* fa = F + (size_t)j * Dd + e0;
    float4 ge = *(const float4*)(gene_emb + (size_t)g * Dd + e0);
    float4 a  = *(const float4*)fa;
    float4 bv = *(const float4*)(fa + Dd);
    o.x = ge.x + a.x + (bv.x - a.x) * t;
    o.y = ge.y + a.y + (bv.y - a.y) * t;
    o.z = ge.z + a.z + (bv.z - a.z) * t;
    o.w = ge.w + a.w + (bv.w - a.w) * t;
  }
  *(float4*)op = o;
}

extern "C" void kernel_launch(void* const* d_in, const int* in_sizes, int n_in,
                              void* d_out, int out_size, void* d_ws, size_t ws_size,
                              hipStream_t stream)
{
  const float* expr     = (const float*)d_in[0];
  const float* gene_emb = (const float*)d_in[1];
  const float* w1       = (const float*)d_in[2];
  const float* b1       = (const float*)d_in[3];
  const float* w2       = (const float*)d_in[4];
  const float* b2       = (const float*)d_in[5];
  const float* cls      = (const float*)d_in[6];
  float* out = (float*)d_out;

  float* F        = (float*)d_ws;                               // 1.05 MB
  int*   comp_idx = (int*)((char*)d_ws + (1280 << 10));         // 128 KB
  float* expr_sel = (float*)((char*)d_ws + (1408 << 10));       // 128 KB

  hipLaunchKernelGGL(k_main,   dim3(Bsz + 257),      dim3(1024), 0, stream,
                     expr, w1, b1, w2, b2, cls, comp_idx, expr_sel, F, out);
  hipLaunchKernelGGL(k_gather, dim3((Bsz * Kk) / 4), dim3(256),  0, stream,
                     comp_idx, expr_sel, F, gene_emb, out);
}